// Round 1
// baseline (1902.646 us; speedup 1.0000x reference)
//
#include <hip/hip_runtime.h>
#include <math.h>

#define DIM   256
#define NHEAD 8
#define HD    32
#define SEQ   1024
#define BATCH 4
#define ROWS  (BATCH * SEQ)   // 4096
#define FFND  1024
#define ATT_SCALE 0.17677669529663687f  // 32^-0.5

// ---------------------------------------------------------------- utilities
__device__ __forceinline__ float wave_reduce_sum(float v) {
    #pragma unroll
    for (int off = 32; off >= 1; off >>= 1) v += __shfl_xor(v, off, 64);
    return v;
}

// ---------------------------------------------------------------- LayerNorm
// One wave per row (DIM=256 -> 4 floats/lane as float4). Block=256 -> 4 rows.
__global__ __launch_bounds__(256) void ln_kernel(
        const float* __restrict__ x, const float* __restrict__ g,
        const float* __restrict__ b, float* __restrict__ y) {
    const int wid  = threadIdx.x >> 6;
    const int lane = threadIdx.x & 63;
    const int row  = blockIdx.x * 4 + wid;
    float4 xv = ((const float4*)(x + (size_t)row * DIM))[lane];
    float s = xv.x + xv.y + xv.z + xv.w;
    s = wave_reduce_sum(s);
    const float mu = s * (1.0f / DIM);
    const float dx = xv.x - mu, dy = xv.y - mu, dz = xv.z - mu, dw = xv.w - mu;
    float sq = dx * dx + dy * dy + dz * dz + dw * dw;
    sq = wave_reduce_sum(sq);
    const float rs = rsqrtf(sq * (1.0f / DIM) + 1e-5f);
    const float4 gv = ((const float4*)g)[lane];
    const float4 bv = ((const float4*)b)[lane];
    float4 o;
    o.x = dx * rs * gv.x + bv.x;
    o.y = dy * rs * gv.y + bv.y;
    o.z = dz * rs * gv.z + bv.z;
    o.w = dw * rs * gv.w + bv.w;
    ((float4*)(y + (size_t)row * DIM))[lane] = o;
}

// ---------------------------------------------------------------- GEMM fp32
// C[M,N] = act(A[M,K] @ W[K,N] + bias[N]) (+ res[M,N]).  64x64 tile, BK=16,
// 256 threads, 4x4 micro-tile per thread.
template <bool GELU>
__global__ __launch_bounds__(256) void gemm_kernel(
        const float* __restrict__ A, const float* __restrict__ W,
        const float* __restrict__ bias, const float* __restrict__ res,
        float* __restrict__ C, int M, int N, int K) {
    __shared__ float As[16][65];   // [k][m]
    __shared__ float Ws[16][65];   // [k][n]
    const int t  = threadIdx.x;
    const int ty = t >> 4, tx = t & 15;
    const int m0 = blockIdx.y * 64;
    const int n0 = blockIdx.x * 64;
    float acc[4][4] = {};

    for (int k0 = 0; k0 < K; k0 += 16) {
        {   // A tile: 64 rows x 16 k
            const int mm = t >> 4, kk = t & 15;
            #pragma unroll
            for (int i = 0; i < 4; i++)
                As[kk][mm + i * 16] = A[(size_t)(m0 + mm + i * 16) * K + k0 + kk];
        }
        {   // W tile: 16 k x 64 cols
            const int nn = t & 63, kb = t >> 6;
            #pragma unroll
            for (int i = 0; i < 4; i++)
                Ws[kb + i * 4][nn] = W[(size_t)(k0 + kb + i * 4) * N + n0 + nn];
        }
        __syncthreads();
        #pragma unroll
        for (int kk = 0; kk < 16; kk++) {
            float a[4], w[4];
            #pragma unroll
            for (int i = 0; i < 4; i++) a[i] = As[kk][ty * 4 + i];
            #pragma unroll
            for (int j = 0; j < 4; j++) w[j] = Ws[kk][tx * 4 + j];
            #pragma unroll
            for (int i = 0; i < 4; i++)
                #pragma unroll
                for (int j = 0; j < 4; j++)
                    acc[i][j] = fmaf(a[i], w[j], acc[i][j]);
        }
        __syncthreads();
    }

    #pragma unroll
    for (int i = 0; i < 4; i++) {
        const int m = m0 + ty * 4 + i;
        #pragma unroll
        for (int j = 0; j < 4; j++) {
            const int n = n0 + tx * 4 + j;
            float v = acc[i][j] + bias[n];
            if (GELU) v = v * 0.5f * (1.0f + erff(v * 0.70710678118654752f));
            if (res) v += res[(size_t)m * N + n];
            C[(size_t)m * N + n] = v;
        }
    }
}

// ---------------------------------------------------------------- Attention
// Flash-style. Grid (SEQ/64, BATCH*NHEAD), 256 threads. Per block: 64 Q rows
// of one (b,h). Online softmax over 16 key tiles of 64. bias may be null.
__global__ __launch_bounds__(256) void attn_kernel(
        const float* __restrict__ q, const float* __restrict__ k,
        const float* __restrict__ v, const float* __restrict__ bias,
        float* __restrict__ out) {
    __shared__ float Qs[64][33];
    __shared__ float Ks[64][33];
    __shared__ float Vs[64][33];
    __shared__ float Ps[64][65];
    const int t  = threadIdx.x;
    const int bh = blockIdx.y;           // b*NHEAD + h
    const int b  = bh >> 3, h = bh & 7;
    const int q0 = blockIdx.x * 64;
    const int rowbase = b * SEQ;
    const int col = h * HD;

    #pragma unroll
    for (int i = 0; i < 8; i++) {        // Q tile 64x32
        const int idx = t + i * 256;
        const int r = idx >> 5, d = idx & 31;
        Qs[r][d] = q[(size_t)(rowbase + q0 + r) * DIM + col + d];
    }
    const int ty = t >> 4, tx = t & 15;
    float m_i[4], l_i[4], o[4][2];
    #pragma unroll
    for (int i = 0; i < 4; i++) { m_i[i] = -1e30f; l_i[i] = 0.f; o[i][0] = 0.f; o[i][1] = 0.f; }
    const float* brow = bias ? bias + ((size_t)bh * SEQ + q0) * SEQ : nullptr;

    for (int kt = 0; kt < SEQ / 64; kt++) {
        __syncthreads();                 // prev PV done: Ks/Vs/Ps reusable
        #pragma unroll
        for (int i = 0; i < 8; i++) {
            const int idx = t + i * 256;
            const int r = idx >> 5, d = idx & 31;
            Ks[r][d] = k[(size_t)(rowbase + kt * 64 + r) * DIM + col + d];
            Vs[r][d] = v[(size_t)(rowbase + kt * 64 + r) * DIM + col + d];
        }
        __syncthreads();

        float s[4][4] = {};
        #pragma unroll
        for (int d = 0; d < 32; d++) {
            float qv[4], kv[4];
            #pragma unroll
            for (int i = 0; i < 4; i++) qv[i] = Qs[ty * 4 + i][d];
            #pragma unroll
            for (int j = 0; j < 4; j++) kv[j] = Ks[tx * 4 + j][d];
            #pragma unroll
            for (int i = 0; i < 4; i++)
                #pragma unroll
                for (int j = 0; j < 4; j++)
                    s[i][j] = fmaf(qv[i], kv[j], s[i][j]);
        }
        #pragma unroll
        for (int i = 0; i < 4; i++)
            #pragma unroll
            for (int j = 0; j < 4; j++) {
                float vv = s[i][j] * ATT_SCALE;
                if (brow) vv += brow[(size_t)(ty * 4 + i) * SEQ + kt * 64 + tx * 4 + j];
                s[i][j] = vv;
            }

        // online softmax (row groups: 16 threads sharing ty, lanes differ in
        // low 4 bits -> shfl_xor 1,2,4,8 stays in-group)
        #pragma unroll
        for (int i = 0; i < 4; i++) {
            float lm = fmaxf(fmaxf(s[i][0], s[i][1]), fmaxf(s[i][2], s[i][3]));
            #pragma unroll
            for (int off = 1; off < 16; off <<= 1) lm = fmaxf(lm, __shfl_xor(lm, off, 64));
            const float mnew = fmaxf(m_i[i], lm);
            const float alpha = expf(m_i[i] - mnew);
            float ls = 0.f;
            #pragma unroll
            for (int j = 0; j < 4; j++) {
                const float p = expf(s[i][j] - mnew);
                s[i][j] = p;
                ls += p;
            }
            #pragma unroll
            for (int off = 1; off < 16; off <<= 1) ls += __shfl_xor(ls, off, 64);
            l_i[i] = l_i[i] * alpha + ls;
            m_i[i] = mnew;
            o[i][0] *= alpha; o[i][1] *= alpha;
            #pragma unroll
            for (int j = 0; j < 4; j++) Ps[ty * 4 + i][tx * 4 + j] = s[i][j];
        }
        __syncthreads();

        // PV: o[r][d] += sum_c P[r][c] * V[c][d]; thread owns rows ty*4..+3,
        // cols tx*2, tx*2+1
        #pragma unroll 8
        for (int c = 0; c < 64; c++) {
            const float vv0 = Vs[c][tx * 2];
            const float vv1 = Vs[c][tx * 2 + 1];
            #pragma unroll
            for (int i = 0; i < 4; i++) {
                const float p = Ps[ty * 4 + i][c];
                o[i][0] = fmaf(p, vv0, o[i][0]);
                o[i][1] = fmaf(p, vv1, o[i][1]);
            }
        }
    }

    #pragma unroll
    for (int i = 0; i < 4; i++) {
        const float inv = 1.0f / l_i[i];
        const int r = q0 + ty * 4 + i;
        out[(size_t)(rowbase + r) * DIM + col + tx * 2]     = o[i][0] * inv;
        out[(size_t)(rowbase + r) * DIM + col + tx * 2 + 1] = o[i][1] * inv;
    }
}

// ---------------------------------------------------------------- launcher
extern "C" void kernel_launch(void* const* d_in, const int* in_sizes, int n_in,
                              void* d_out, int out_size, void* d_ws, size_t ws_size,
                              hipStream_t stream) {
    const float* src_feats    = (const float*)d_in[0];
    const float* tgt_feats    = (const float*)d_in[1];
    const float* src_geo_bias = (const float*)d_in[2];
    const float* tgt_geo_bias = (const float*)d_in[3];
    const float* sa_q_w = (const float*)d_in[4];
    const float* sa_q_b = (const float*)d_in[5];
    const float* sa_k_w = (const float*)d_in[6];
    const float* sa_k_b = (const float*)d_in[7];
    const float* sa_v_w = (const float*)d_in[8];
    const float* sa_v_b = (const float*)d_in[9];
    const float* sa_o_w = (const float*)d_in[10];
    const float* sa_o_b = (const float*)d_in[11];
    const float* ca_q_w = (const float*)d_in[12];
    const float* ca_q_b = (const float*)d_in[13];
    const float* ca_k_w = (const float*)d_in[14];
    const float* ca_k_b = (const float*)d_in[15];
    const float* ca_v_w = (const float*)d_in[16];
    const float* ca_v_b = (const float*)d_in[17];
    const float* ca_o_w = (const float*)d_in[18];
    const float* ca_o_b = (const float*)d_in[19];
    const float* ln_sa_g = (const float*)d_in[20];
    const float* ln_sa_b = (const float*)d_in[21];
    const float* ln_ca_g = (const float*)d_in[22];
    const float* ln_ca_b = (const float*)d_in[23];
    const float* ln_ff_g = (const float*)d_in[24];
    const float* ln_ff_b = (const float*)d_in[25];
    const float* ffn_w1  = (const float*)d_in[26];
    const float* ffn_b1  = (const float*)d_in[27];
    const float* ffn_w2  = (const float*)d_in[28];
    const float* ffn_b2  = (const float*)d_in[29];

    float* out_src = (float*)d_out;
    float* out_tgt = out_src + (size_t)ROWS * DIM;

    float* ws  = (float*)d_ws;
    const size_t T = (size_t)ROWS * DIM;     // 1M floats
    float* XnA = ws;                         // LN buffer A
    float* XnB = ws + T;                     // LN buffer B
    float* Qb  = ws + 2 * T;
    float* Kb  = ws + 3 * T;
    float* Vb  = ws + 4 * T;
    float* AO  = ws + 5 * T;
    float* Hh  = Qb;                         // FFN hidden (4096x1024) aliases Q..AO

    const dim3 blk(256);
    const dim3 ln_grid(ROWS / 4);
    const dim3 attn_grid(SEQ / 64, BATCH * NHEAD);

    auto gemm = [&](const float* A, const float* W, const float* bias,
                    const float* res, float* C, int M, int N, int K, bool gelu) {
        dim3 g(N / 64, M / 64);
        if (gelu) gemm_kernel<true><<<g, blk, 0, stream>>>(A, W, bias, res, C, M, N, K);
        else      gemm_kernel<false><<<g, blk, 0, stream>>>(A, W, bias, res, C, M, N, K);
    };

    // ---- 1. geometric self-attention (src) ----
    ln_kernel<<<ln_grid, blk, 0, stream>>>(src_feats, ln_sa_g, ln_sa_b, XnA);
    gemm(XnA, sa_q_w, sa_q_b, nullptr, Qb, ROWS, DIM, DIM, false);
    gemm(XnA, sa_k_w, sa_k_b, nullptr, Kb, ROWS, DIM, DIM, false);
    gemm(XnA, sa_v_w, sa_v_b, nullptr, Vb, ROWS, DIM, DIM, false);
    attn_kernel<<<attn_grid, blk, 0, stream>>>(Qb, Kb, Vb, src_geo_bias, AO);
    gemm(AO, sa_o_w, sa_o_b, src_feats, out_src, ROWS, DIM, DIM, false);

    // ---- 1. geometric self-attention (tgt) ----
    ln_kernel<<<ln_grid, blk, 0, stream>>>(tgt_feats, ln_sa_g, ln_sa_b, XnA);
    gemm(XnA, sa_q_w, sa_q_b, nullptr, Qb, ROWS, DIM, DIM, false);
    gemm(XnA, sa_k_w, sa_k_b, nullptr, Kb, ROWS, DIM, DIM, false);
    gemm(XnA, sa_v_w, sa_v_b, nullptr, Vb, ROWS, DIM, DIM, false);
    attn_kernel<<<attn_grid, blk, 0, stream>>>(Qb, Kb, Vb, tgt_geo_bias, AO);
    gemm(AO, sa_o_w, sa_o_b, tgt_feats, out_tgt, ROWS, DIM, DIM, false);

    // ---- 2. cross-attention (both normed feats computed first) ----
    ln_kernel<<<ln_grid, blk, 0, stream>>>(out_src, ln_ca_g, ln_ca_b, XnA);  // src_n
    ln_kernel<<<ln_grid, blk, 0, stream>>>(out_tgt, ln_ca_g, ln_ca_b, XnB);  // tgt_n

    // src attends to tgt_n
    gemm(XnA, ca_q_w, ca_q_b, nullptr, Qb, ROWS, DIM, DIM, false);
    gemm(XnB, ca_k_w, ca_k_b, nullptr, Kb, ROWS, DIM, DIM, false);
    gemm(XnB, ca_v_w, ca_v_b, nullptr, Vb, ROWS, DIM, DIM, false);
    attn_kernel<<<attn_grid, blk, 0, stream>>>(Qb, Kb, Vb, nullptr, AO);
    gemm(AO, ca_o_w, ca_o_b, out_src, out_src, ROWS, DIM, DIM, false);

    // tgt attends to src_n
    gemm(XnB, ca_q_w, ca_q_b, nullptr, Qb, ROWS, DIM, DIM, false);
    gemm(XnA, ca_k_w, ca_k_b, nullptr, Kb, ROWS, DIM, DIM, false);
    gemm(XnA, ca_v_w, ca_v_b, nullptr, Vb, ROWS, DIM, DIM, false);
    attn_kernel<<<attn_grid, blk, 0, stream>>>(Qb, Kb, Vb, nullptr, AO);
    gemm(AO, ca_o_w, ca_o_b, out_tgt, out_tgt, ROWS, DIM, DIM, false);

    // ---- 3. FFN ----
    ln_kernel<<<ln_grid, blk, 0, stream>>>(out_src, ln_ff_g, ln_ff_b, XnA);
    gemm(XnA, ffn_w1, ffn_b1, nullptr, Hh, ROWS, FFND, DIM, true);
    gemm(Hh, ffn_w2, ffn_b2, out_src, out_src, ROWS, DIM, FFND, false);

    ln_kernel<<<ln_grid, blk, 0, stream>>>(out_tgt, ln_ff_g, ln_ff_b, XnA);
    gemm(XnA, ffn_w1, ffn_b1, nullptr, Hh, ROWS, FFND, DIM, true);
    gemm(Hh, ffn_w2, ffn_b2, out_tgt, out_tgt, ROWS, DIM, FFND, false);
}

// Round 2
// 538.821 us; speedup vs baseline: 3.5311x; 3.5311x over previous
//
#include <hip/hip_runtime.h>
#include <math.h>

#define DIM   256
#define NHEAD 8
#define HD    32
#define SEQ   1024
#define BATCH 4
#define ROWS  (BATCH * SEQ)       // 4096 per side
#define ROWS2 (2 * ROWS)          // 8192 (src+tgt batched)
#define FFND  1024
#define QKVN  768
#define ATT_SCALE 0.17677669529663687f  // 32^-0.5

typedef __attribute__((ext_vector_type(8))) short   bf16x8;
typedef __attribute__((ext_vector_type(4))) float   f32x4;

__device__ __forceinline__ unsigned short f2bf(float x) {
    unsigned u = __float_as_uint(x);
    unsigned r = (u + 0x7fffu + ((u >> 16) & 1u)) >> 16;   // RNE
    return (unsigned short)r;
}

// ---------------------------------------------------------------- LayerNorm
// One wave per row; block=256 -> 4 rows. fp32 in, bf16 out.
__global__ __launch_bounds__(256) void ln_kernel(
        const float* __restrict__ x, const float* __restrict__ g,
        const float* __restrict__ b, unsigned short* __restrict__ y) {
    const int wid  = threadIdx.x >> 6;
    const int lane = threadIdx.x & 63;
    const int row  = blockIdx.x * 4 + wid;
    float4 xv = ((const float4*)(x + (size_t)row * DIM))[lane];
    float s = xv.x + xv.y + xv.z + xv.w;
    #pragma unroll
    for (int off = 32; off >= 1; off >>= 1) s += __shfl_xor(s, off, 64);
    const float mu = s * (1.0f / DIM);
    const float dx = xv.x - mu, dy = xv.y - mu, dz = xv.z - mu, dw = xv.w - mu;
    float sq = dx * dx + dy * dy + dz * dz + dw * dw;
    #pragma unroll
    for (int off = 32; off >= 1; off >>= 1) sq += __shfl_xor(sq, off, 64);
    const float rs = rsqrtf(sq * (1.0f / DIM) + 1e-5f);
    const float4 gv = ((const float4*)g)[lane];
    const float4 bv = ((const float4*)b)[lane];
    ushort4 o;
    o.x = f2bf(dx * rs * gv.x + bv.x);
    o.y = f2bf(dy * rs * gv.y + bv.y);
    o.z = f2bf(dz * rs * gv.z + bv.z);
    o.w = f2bf(dw * rs * gv.w + bv.w);
    ((ushort4*)(y + (size_t)row * DIM))[lane] = o;
}

// ---------------------------------------------------------------- weight cvt
// fp32 -> bf16, transposed to [N][K]; QKV weights/biases concatenated.
__global__ __launch_bounds__(256) void convert_weights(
        const float* __restrict__ sa_q_w, const float* __restrict__ sa_k_w,
        const float* __restrict__ sa_v_w, const float* __restrict__ ca_q_w,
        const float* __restrict__ ca_k_w, const float* __restrict__ ca_v_w,
        const float* __restrict__ sa_o_w, const float* __restrict__ ca_o_w,
        const float* __restrict__ ffn_w1, const float* __restrict__ ffn_w2,
        const float* __restrict__ sa_q_b, const float* __restrict__ sa_k_b,
        const float* __restrict__ sa_v_b, const float* __restrict__ ca_q_b,
        const float* __restrict__ ca_k_b, const float* __restrict__ ca_v_b,
        unsigned short* __restrict__ sa_qkv_wt, unsigned short* __restrict__ ca_qkv_wt,
        unsigned short* __restrict__ sa_o_wt,   unsigned short* __restrict__ ca_o_wt,
        unsigned short* __restrict__ ffn1_wt,   unsigned short* __restrict__ ffn2_wt,
        float* __restrict__ sa_qkv_bias, float* __restrict__ ca_qkv_bias) {
    int gid = blockIdx.x * 256 + threadIdx.x;
    if (gid < 196608) {                      // sa qkv wt: [768][256]
        int n = gid >> 8, k = gid & 255, nn = n & 255;
        const float* w = (n < 256) ? sa_q_w : (n < 512) ? sa_k_w : sa_v_w;
        sa_qkv_wt[gid] = f2bf(w[k * 256 + nn]);
        return;
    }
    gid -= 196608;
    if (gid < 196608) {                      // ca qkv wt
        int n = gid >> 8, k = gid & 255, nn = n & 255;
        const float* w = (n < 256) ? ca_q_w : (n < 512) ? ca_k_w : ca_v_w;
        ca_qkv_wt[gid] = f2bf(w[k * 256 + nn]);
        return;
    }
    gid -= 196608;
    if (gid < 65536) { int n = gid >> 8, k = gid & 255; sa_o_wt[gid] = f2bf(sa_o_w[k * 256 + n]); return; }
    gid -= 65536;
    if (gid < 65536) { int n = gid >> 8, k = gid & 255; ca_o_wt[gid] = f2bf(ca_o_w[k * 256 + n]); return; }
    gid -= 65536;
    if (gid < 262144) { int n = gid >> 8,  k = gid & 255;  ffn1_wt[gid] = f2bf(ffn_w1[k * 1024 + n]); return; }
    gid -= 262144;
    if (gid < 262144) { int n = gid >> 10, k = gid & 1023; ffn2_wt[gid] = f2bf(ffn_w2[k * 256 + n]);  return; }
    gid -= 262144;
    if (gid < 768) {
        sa_qkv_bias[gid] = (gid < 256) ? sa_q_b[gid] : (gid < 512) ? sa_k_b[gid - 256] : sa_v_b[gid - 512];
        return;
    }
    gid -= 768;
    if (gid < 768) {
        ca_qkv_bias[gid] = (gid < 256) ? ca_q_b[gid] : (gid < 512) ? ca_k_b[gid - 256] : ca_v_b[gid - 512];
    }
}

// ---------------------------------------------------------------- bf16 GEMM
// C[M,N] = act(A[M,K] @ Wt[N,K]^T + bias[N]) (+ res).  64x64 tile, BK=64,
// 4 waves (2x2), each 32x32 via 2x2 MFMA 16x16x32.  A, Wt bf16 row-major.
template <bool GELU, bool OUT_BF16>
__global__ __launch_bounds__(256) void gemm_bf16(
        const unsigned short* __restrict__ A, const unsigned short* __restrict__ Wt,
        const float* __restrict__ bias,
        const float* __restrict__ res_lo, const float* __restrict__ res_hi,
        float* __restrict__ Cf, unsigned short* __restrict__ Cb,
        int N, int K, int rsplit) {
    __shared__ unsigned short As[64][72];
    __shared__ unsigned short Ws[64][72];
    const int t = threadIdx.x;
    const int w = t >> 6, lane = t & 63, quad = lane >> 4, l16 = lane & 15;
    const int wm = w >> 1, wn = w & 1;
    const int m0 = blockIdx.y * 64, n0 = blockIdx.x * 64;
    const int ar = t >> 2, ac = (t & 3) * 8;

    f32x4 acc[2][2];
    #pragma unroll
    for (int i = 0; i < 2; i++)
        #pragma unroll
        for (int j = 0; j < 2; j++)
            acc[i][j] = (f32x4){0.f, 0.f, 0.f, 0.f};

    for (int k0 = 0; k0 < K; k0 += 64) {
        *(bf16x8*)&As[ar][ac]      = *(const bf16x8*)&A [(size_t)(m0 + ar) * K + k0 + ac];
        *(bf16x8*)&As[ar][ac + 32] = *(const bf16x8*)&A [(size_t)(m0 + ar) * K + k0 + ac + 32];
        *(bf16x8*)&Ws[ar][ac]      = *(const bf16x8*)&Wt[(size_t)(n0 + ar) * K + k0 + ac];
        *(bf16x8*)&Ws[ar][ac + 32] = *(const bf16x8*)&Wt[(size_t)(n0 + ar) * K + k0 + ac + 32];
        __syncthreads();
        #pragma unroll
        for (int kc = 0; kc < 2; kc++) {
            bf16x8 af[2], bfr[2];
            #pragma unroll
            for (int i = 0; i < 2; i++) {
                af[i]  = *(const bf16x8*)&As[wm * 32 + i * 16 + l16][kc * 32 + quad * 8];
                bfr[i] = *(const bf16x8*)&Ws[wn * 32 + i * 16 + l16][kc * 32 + quad * 8];
            }
            #pragma unroll
            for (int i = 0; i < 2; i++)
                #pragma unroll
                for (int j = 0; j < 2; j++)
                    acc[i][j] = __builtin_amdgcn_mfma_f32_16x16x32_bf16(af[i], bfr[j], acc[i][j], 0, 0, 0);
        }
        __syncthreads();
    }

    const float* res = nullptr;
    if (!OUT_BF16 && res_lo)
        res = (m0 < rsplit) ? res_lo : (res_hi - (size_t)rsplit * N);

    #pragma unroll
    for (int i = 0; i < 2; i++) {
        #pragma unroll
        for (int j = 0; j < 2; j++) {
            const int n = n0 + wn * 32 + j * 16 + l16;
            const float bv = bias[n];
            #pragma unroll
            for (int r = 0; r < 4; r++) {
                const int m = m0 + wm * 32 + i * 16 + quad * 4 + r;
                float v = acc[i][j][r] + bv;
                if (GELU) v = 0.5f * v * (1.0f + erff(v * 0.70710678118654752f));
                if (OUT_BF16) {
                    Cb[(size_t)m * N + n] = f2bf(v);
                } else {
                    if (res) v += res[(size_t)m * N + n];
                    Cf[(size_t)m * N + n] = v;
                }
            }
        }
    }
}

// ---------------------------------------------------------------- attention
// MFMA flash attention.  QKV: bf16 [8192][768] (Q|K|V).  Grid (16, 64):
// x = q-tile (64 rows), y = bh (side*32 + b*8 + h).  4 waves, 16 q-rows each.
// HD=32 -> QK^T is one 16x16x32 MFMA per 16-key subtile.
template <bool HAS_BIAS>
__global__ __launch_bounds__(256) void attn_mfma(
        const unsigned short* __restrict__ qkv,
        const float* __restrict__ bias_src, const float* __restrict__ bias_tgt,
        unsigned short* __restrict__ AO, int cross) {
    __shared__ unsigned short Ks[64][40];   // [key][hd]
    __shared__ unsigned short Vt[32][72];   // [hd][key]  (transposed)
    __shared__ unsigned short Ps[64][72];   // [q][key]   (wave-private 16-row bands)
    const int t = threadIdx.x;
    const int w = t >> 6, lane = t & 63, quad = lane >> 4, l16 = lane & 15;
    const int bh = blockIdx.y;
    const int side = bh >> 5, b = (bh >> 3) & 3, h = bh & 7;
    const int q0 = blockIdx.x * 64;
    const int qbase  = side * ROWS + b * SEQ;
    const int kvbase = (cross ? (1 - side) : side) * ROWS + b * SEQ;
    const float* brow = nullptr;
    if (HAS_BIAS) {
        const float* bp = side ? bias_tgt : bias_src;
        brow = bp + ((size_t)(b * NHEAD + h) * SEQ + q0 + w * 16) * SEQ;
    }
    // Q fragment straight from global (A-operand layout, 16B aligned)
    bf16x8 aq = *(const bf16x8*)&qkv[(size_t)(qbase + q0 + w * 16 + l16) * QKVN + h * HD + quad * 8];

    f32x4 o0 = (f32x4){0.f, 0.f, 0.f, 0.f};
    f32x4 o1 = (f32x4){0.f, 0.f, 0.f, 0.f};
    float m_i[4], l_i[4];
    #pragma unroll
    for (int r = 0; r < 4; r++) { m_i[r] = -1e30f; l_i[r] = 0.f; }

    const int sr = t >> 2, sc = (t & 3) * 8;

    for (int kt = 0; kt < SEQ / 64; kt++) {
        __syncthreads();
        // stage K [64 keys][32 hd]
        *(bf16x8*)&Ks[sr][sc] =
            *(const bf16x8*)&qkv[(size_t)(kvbase + kt * 64 + sr) * QKVN + DIM + h * HD + sc];
        // stage V transposed: Vt[d][key]
        {
            bf16x8 vv = *(const bf16x8*)&qkv[(size_t)(kvbase + kt * 64 + sr) * QKVN + 2 * DIM + h * HD + sc];
            #pragma unroll
            for (int j = 0; j < 8; j++) Vt[sc + j][sr] = ((unsigned short*)&vv)[j];
        }
        __syncthreads();

        // S = Q @ K^T  (4 key-subtiles of 16)
        f32x4 s[4];
        #pragma unroll
        for (int st = 0; st < 4; st++) {
            bf16x8 kf = *(const bf16x8*)&Ks[st * 16 + l16][quad * 8];
            f32x4 z = (f32x4){0.f, 0.f, 0.f, 0.f};
            s[st] = __builtin_amdgcn_mfma_f32_16x16x32_bf16(aq, kf, z, 0, 0, 0);
        }
        #pragma unroll
        for (int st = 0; st < 4; st++)
            #pragma unroll
            for (int r = 0; r < 4; r++) {
                float v = s[st][r] * ATT_SCALE;
                if (HAS_BIAS)
                    v += brow[(size_t)(quad * 4 + r) * SEQ + kt * 64 + st * 16 + l16];
                s[st][r] = v;
            }

        // online softmax: rows live across the 16 lanes sharing `quad`
        float alpha[4];
        #pragma unroll
        for (int r = 0; r < 4; r++) {
            float lm = fmaxf(fmaxf(s[0][r], s[1][r]), fmaxf(s[2][r], s[3][r]));
            #pragma unroll
            for (int off = 1; off < 16; off <<= 1) lm = fmaxf(lm, __shfl_xor(lm, off, 64));
            const float mnew = fmaxf(m_i[r], lm);
            alpha[r] = __expf(m_i[r] - mnew);
            float ls = 0.f;
            #pragma unroll
            for (int st = 0; st < 4; st++) {
                const float p = __expf(s[st][r] - mnew);
                s[st][r] = p;
                ls += p;
            }
            #pragma unroll
            for (int off = 1; off < 16; off <<= 1) ls += __shfl_xor(ls, off, 64);
            l_i[r] = l_i[r] * alpha[r] + ls;
            m_i[r] = mnew;
        }
        #pragma unroll
        for (int r = 0; r < 4; r++) { o0[r] *= alpha[r]; o1[r] *= alpha[r]; }

        // P -> LDS (bf16, wave-private band), then PV via MFMA
        #pragma unroll
        for (int st = 0; st < 4; st++)
            #pragma unroll
            for (int r = 0; r < 4; r++)
                Ps[w * 16 + quad * 4 + r][st * 16 + l16] = f2bf(s[st][r]);

        #pragma unroll
        for (int c = 0; c < 2; c++) {
            bf16x8 ap  = *(const bf16x8*)&Ps[w * 16 + l16][c * 32 + quad * 8];
            bf16x8 bv0 = *(const bf16x8*)&Vt[l16][c * 32 + quad * 8];
            bf16x8 bv1 = *(const bf16x8*)&Vt[16 + l16][c * 32 + quad * 8];
            o0 = __builtin_amdgcn_mfma_f32_16x16x32_bf16(ap, bv0, o0, 0, 0, 0);
            o1 = __builtin_amdgcn_mfma_f32_16x16x32_bf16(ap, bv1, o1, 0, 0, 0);
        }
    }

    #pragma unroll
    for (int r = 0; r < 4; r++) {
        const float inv = 1.0f / l_i[r];
        const size_t orow = (size_t)(qbase + q0 + w * 16 + quad * 4 + r) * DIM + h * HD;
        AO[orow + l16]      = f2bf(o0[r] * inv);
        AO[orow + 16 + l16] = f2bf(o1[r] * inv);
    }
}

// ---------------------------------------------------------------- launcher
extern "C" void kernel_launch(void* const* d_in, const int* in_sizes, int n_in,
                              void* d_out, int out_size, void* d_ws, size_t ws_size,
                              hipStream_t stream) {
    const float* src_feats    = (const float*)d_in[0];
    const float* tgt_feats    = (const float*)d_in[1];
    const float* src_geo_bias = (const float*)d_in[2];
    const float* tgt_geo_bias = (const float*)d_in[3];
    const float* sa_q_w = (const float*)d_in[4];
    const float* sa_q_b = (const float*)d_in[5];
    const float* sa_k_w = (const float*)d_in[6];
    const float* sa_k_b = (const float*)d_in[7];
    const float* sa_v_w = (const float*)d_in[8];
    const float* sa_v_b = (const float*)d_in[9];
    const float* sa_o_w = (const float*)d_in[10];
    const float* sa_o_b = (const float*)d_in[11];
    const float* ca_q_w = (const float*)d_in[12];
    const float* ca_q_b = (const float*)d_in[13];
    const float* ca_k_w = (const float*)d_in[14];
    const float* ca_k_b = (const float*)d_in[15];
    const float* ca_v_w = (const float*)d_in[16];
    const float* ca_v_b = (const float*)d_in[17];
    const float* ca_o_w = (const float*)d_in[18];
    const float* ca_o_b = (const float*)d_in[19];
    const float* ln_sa_g = (const float*)d_in[20];
    const float* ln_sa_b = (const float*)d_in[21];
    const float* ln_ca_g = (const float*)d_in[22];
    const float* ln_ca_b = (const float*)d_in[23];
    const float* ln_ff_g = (const float*)d_in[24];
    const float* ln_ff_b = (const float*)d_in[25];
    const float* ffn_w1  = (const float*)d_in[26];
    const float* ffn_b1  = (const float*)d_in[27];
    const float* ffn_w2  = (const float*)d_in[28];
    const float* ffn_b2  = (const float*)d_in[29];

    float* out = (float*)d_out;                     // [8192][256] fp32 (src|tgt)

    // ---- workspace carve (bytes) ----
    char* ws = (char*)d_ws;
    unsigned short* Xn   = (unsigned short*)(ws);                    //  4 MB  [8192][256] bf16
    unsigned short* QKV  = (unsigned short*)(ws + (4 << 20));        // 12 MB  [8192][768] bf16
    unsigned short* AO   = (unsigned short*)(ws + (16 << 20));       //  4 MB  [8192][256] bf16
    unsigned short* Hh   = (unsigned short*)(ws + (4 << 20));        // 16 MB  [8192][1024] bf16 (aliases QKV+AO)
    char* wp = ws + (20 << 20);
    unsigned short* sa_qkv_wt = (unsigned short*)wp;  wp += 768 * 256 * 2;
    unsigned short* ca_qkv_wt = (unsigned short*)wp;  wp += 768 * 256 * 2;
    unsigned short* sa_o_wt   = (unsigned short*)wp;  wp += 256 * 256 * 2;
    unsigned short* ca_o_wt   = (unsigned short*)wp;  wp += 256 * 256 * 2;
    unsigned short* ffn1_wt   = (unsigned short*)wp;  wp += 1024 * 256 * 2;
    unsigned short* ffn2_wt   = (unsigned short*)wp;  wp += 256 * 1024 * 2;
    float* sa_qkv_bias = (float*)wp;  wp += 768 * 4;
    float* ca_qkv_bias = (float*)wp;  wp += 768 * 4;

    const dim3 blk(256);
    const dim3 attn_grid(SEQ / 64, 64);

    // 0. weight conversion (bf16, transposed, qkv-concat)
    convert_weights<<<dim3(4103), blk, 0, stream>>>(
        sa_q_w, sa_k_w, sa_v_w, ca_q_w, ca_k_w, ca_v_w, sa_o_w, ca_o_w,
        ffn_w1, ffn_w2, sa_q_b, sa_k_b, sa_v_b, ca_q_b, ca_k_b, ca_v_b,
        sa_qkv_wt, ca_qkv_wt, sa_o_wt, ca_o_wt, ffn1_wt, ffn2_wt,
        sa_qkv_bias, ca_qkv_bias);

    // ---- 1. geometric self-attention (src+tgt batched) ----
    ln_kernel<<<dim3(ROWS / 4), blk, 0, stream>>>(src_feats, ln_sa_g, ln_sa_b, Xn);
    ln_kernel<<<dim3(ROWS / 4), blk, 0, stream>>>(tgt_feats, ln_sa_g, ln_sa_b, Xn + (size_t)ROWS * DIM);
    gemm_bf16<false, true><<<dim3(QKVN / 64, ROWS2 / 64), blk, 0, stream>>>(
        Xn, sa_qkv_wt, sa_qkv_bias, nullptr, nullptr, nullptr, QKV, QKVN, DIM, ROWS);
    attn_mfma<true><<<attn_grid, blk, 0, stream>>>(QKV, src_geo_bias, tgt_geo_bias, AO, 0);
    gemm_bf16<false, false><<<dim3(DIM / 64, ROWS2 / 64), blk, 0, stream>>>(
        AO, sa_o_wt, sa_o_b, src_feats, tgt_feats, out, nullptr, DIM, DIM, ROWS);

    // ---- 2. cross-attention ----
    ln_kernel<<<dim3(ROWS2 / 4), blk, 0, stream>>>(out, ln_ca_g, ln_ca_b, Xn);
    gemm_bf16<false, true><<<dim3(QKVN / 64, ROWS2 / 64), blk, 0, stream>>>(
        Xn, ca_qkv_wt, ca_qkv_bias, nullptr, nullptr, nullptr, QKV, QKVN, DIM, ROWS);
    attn_mfma<false><<<attn_grid, blk, 0, stream>>>(QKV, nullptr, nullptr, AO, 1);
    gemm_bf16<false, false><<<dim3(DIM / 64, ROWS2 / 64), blk, 0, stream>>>(
        AO, ca_o_wt, ca_o_b, out, out + (size_t)ROWS * DIM, out, nullptr, DIM, DIM, ROWS);

    // ---- 3. FFN ----
    ln_kernel<<<dim3(ROWS2 / 4), blk, 0, stream>>>(out, ln_ff_g, ln_ff_b, Xn);
    gemm_bf16<true, true><<<dim3(FFND / 64, ROWS2 / 64), blk, 0, stream>>>(
        Xn, ffn1_wt, ffn_b1, nullptr, nullptr, nullptr, Hh, FFND, DIM, ROWS);
    gemm_bf16<false, false><<<dim3(DIM / 64, ROWS2 / 64), blk, 0, stream>>>(
        Hh, ffn2_wt, ffn_b2, out, out + (size_t)ROWS * DIM, out, nullptr, DIM, FFND, ROWS);
}

// Round 3
// 488.464 us; speedup vs baseline: 3.8952x; 1.1031x over previous
//
#include <hip/hip_runtime.h>
#include <math.h>

#define DIM   256
#define NHEAD 8
#define HD    32
#define SEQ   1024
#define BATCH 4
#define ROWS  (BATCH * SEQ)       // 4096 per side
#define ROWS2 (2 * ROWS)          // 8192 (src+tgt batched)
#define FFND  1024
#define QKVN  768
#define ATT_SCALE 0.17677669529663687f  // 32^-0.5

typedef __attribute__((ext_vector_type(8))) short   bf16x8;
typedef __attribute__((ext_vector_type(4))) float   f32x4;

__device__ __forceinline__ unsigned short f2bf(float x) {
    unsigned u = __float_as_uint(x);
    unsigned r = (u + 0x7fffu + ((u >> 16) & 1u)) >> 16;   // RNE
    return (unsigned short)r;
}

// async global->LDS, 16 B per lane. LDS dest = wave-uniform base + lane*16.
typedef const __attribute__((address_space(1))) unsigned int* glds_gp;
typedef __attribute__((address_space(3))) unsigned int*       glds_lp;
__device__ __forceinline__ void glds16(const void* g, void* l) {
    __builtin_amdgcn_global_load_lds((glds_gp)g, (glds_lp)l, 16, 0, 0);
}

// ---------------------------------------------------------------- LayerNorm
// One wave per row; block=256 -> 4 rows. fp32 in, bf16 out.
__global__ __launch_bounds__(256) void ln_kernel(
        const float* __restrict__ x, const float* __restrict__ g,
        const float* __restrict__ b, unsigned short* __restrict__ y) {
    const int wid  = threadIdx.x >> 6;
    const int lane = threadIdx.x & 63;
    const int row  = blockIdx.x * 4 + wid;
    float4 xv = ((const float4*)(x + (size_t)row * DIM))[lane];
    float s = xv.x + xv.y + xv.z + xv.w;
    #pragma unroll
    for (int off = 32; off >= 1; off >>= 1) s += __shfl_xor(s, off, 64);
    const float mu = s * (1.0f / DIM);
    const float dx = xv.x - mu, dy = xv.y - mu, dz = xv.z - mu, dw = xv.w - mu;
    float sq = dx * dx + dy * dy + dz * dz + dw * dw;
    #pragma unroll
    for (int off = 32; off >= 1; off >>= 1) sq += __shfl_xor(sq, off, 64);
    const float rs = rsqrtf(sq * (1.0f / DIM) + 1e-5f);
    const float4 gv = ((const float4*)g)[lane];
    const float4 bv = ((const float4*)b)[lane];
    ushort4 o;
    o.x = f2bf(dx * rs * gv.x + bv.x);
    o.y = f2bf(dy * rs * gv.y + bv.y);
    o.z = f2bf(dz * rs * gv.z + bv.z);
    o.w = f2bf(dw * rs * gv.w + bv.w);
    ((ushort4*)(y + (size_t)row * DIM))[lane] = o;
}

// two-source variant (src_feats | tgt_feats -> one bf16 buffer)
__global__ __launch_bounds__(256) void ln2_kernel(
        const float* __restrict__ x0, const float* __restrict__ x1,
        const float* __restrict__ g, const float* __restrict__ b,
        unsigned short* __restrict__ y) {
    const int wid  = threadIdx.x >> 6;
    const int lane = threadIdx.x & 63;
    const int row  = blockIdx.x * 4 + wid;
    const float* x = (row < ROWS) ? (x0 + (size_t)row * DIM)
                                  : (x1 + (size_t)(row - ROWS) * DIM);
    float4 xv = ((const float4*)x)[lane];
    float s = xv.x + xv.y + xv.z + xv.w;
    #pragma unroll
    for (int off = 32; off >= 1; off >>= 1) s += __shfl_xor(s, off, 64);
    const float mu = s * (1.0f / DIM);
    const float dx = xv.x - mu, dy = xv.y - mu, dz = xv.z - mu, dw = xv.w - mu;
    float sq = dx * dx + dy * dy + dz * dz + dw * dw;
    #pragma unroll
    for (int off = 32; off >= 1; off >>= 1) sq += __shfl_xor(sq, off, 64);
    const float rs = rsqrtf(sq * (1.0f / DIM) + 1e-5f);
    const float4 gv = ((const float4*)g)[lane];
    const float4 bv = ((const float4*)b)[lane];
    ushort4 o;
    o.x = f2bf(dx * rs * gv.x + bv.x);
    o.y = f2bf(dy * rs * gv.y + bv.y);
    o.z = f2bf(dz * rs * gv.z + bv.z);
    o.w = f2bf(dw * rs * gv.w + bv.w);
    ((ushort4*)(y + (size_t)row * DIM))[lane] = o;
}

// ---------------------------------------------------------------- weight cvt
__global__ __launch_bounds__(256) void convert_weights(
        const float* __restrict__ sa_q_w, const float* __restrict__ sa_k_w,
        const float* __restrict__ sa_v_w, const float* __restrict__ ca_q_w,
        const float* __restrict__ ca_k_w, const float* __restrict__ ca_v_w,
        const float* __restrict__ sa_o_w, const float* __restrict__ ca_o_w,
        const float* __restrict__ ffn_w1, const float* __restrict__ ffn_w2,
        const float* __restrict__ sa_q_b, const float* __restrict__ sa_k_b,
        const float* __restrict__ sa_v_b, const float* __restrict__ ca_q_b,
        const float* __restrict__ ca_k_b, const float* __restrict__ ca_v_b,
        unsigned short* __restrict__ sa_qkv_wt, unsigned short* __restrict__ ca_qkv_wt,
        unsigned short* __restrict__ sa_o_wt,   unsigned short* __restrict__ ca_o_wt,
        unsigned short* __restrict__ ffn1_wt,   unsigned short* __restrict__ ffn2_wt,
        float* __restrict__ sa_qkv_bias, float* __restrict__ ca_qkv_bias) {
    int gid = blockIdx.x * 256 + threadIdx.x;
    if (gid < 196608) {                      // sa qkv wt: [768][256]
        int n = gid >> 8, k = gid & 255, nn = n & 255;
        const float* w = (n < 256) ? sa_q_w : (n < 512) ? sa_k_w : sa_v_w;
        sa_qkv_wt[gid] = f2bf(w[k * 256 + nn]);
        return;
    }
    gid -= 196608;
    if (gid < 196608) {                      // ca qkv wt
        int n = gid >> 8, k = gid & 255, nn = n & 255;
        const float* w = (n < 256) ? ca_q_w : (n < 512) ? ca_k_w : ca_v_w;
        ca_qkv_wt[gid] = f2bf(w[k * 256 + nn]);
        return;
    }
    gid -= 196608;
    if (gid < 65536) { int n = gid >> 8, k = gid & 255; sa_o_wt[gid] = f2bf(sa_o_w[k * 256 + n]); return; }
    gid -= 65536;
    if (gid < 65536) { int n = gid >> 8, k = gid & 255; ca_o_wt[gid] = f2bf(ca_o_w[k * 256 + n]); return; }
    gid -= 65536;
    if (gid < 262144) { int n = gid >> 8,  k = gid & 255;  ffn1_wt[gid] = f2bf(ffn_w1[k * 1024 + n]); return; }
    gid -= 262144;
    if (gid < 262144) { int n = gid >> 10, k = gid & 1023; ffn2_wt[gid] = f2bf(ffn_w2[k * 256 + n]);  return; }
    gid -= 262144;
    if (gid < 768) {
        sa_qkv_bias[gid] = (gid < 256) ? sa_q_b[gid] : (gid < 512) ? sa_k_b[gid - 256] : sa_v_b[gid - 512];
        return;
    }
    gid -= 768;
    if (gid < 768) {
        ca_qkv_bias[gid] = (gid < 256) ? ca_q_b[gid] : (gid < 512) ? ca_k_b[gid - 256] : ca_v_b[gid - 512];
    }
}

// ---------------------------------------------------------------- bf16 GEMM
// C = act(A[M,K] @ Wt[N,K]^T + bias) (+res). 64x64 tile, BK=64, 4 waves 2x2.
// global_load_lds staging with XOR chunk swizzle (LDS rows unpadded 128 B).
// MODE 0: f32 out + residual; 1: bf16 out; 2: QKV split (Q,K -> qkout ld 512;
//         V -> vt_g transposed [bh][hd][seq]).
template <bool GELU, int MODE>
__global__ __launch_bounds__(256) void gemm_bf16(
        const unsigned short* __restrict__ A, const unsigned short* __restrict__ Wt,
        const float* __restrict__ bias,
        const float* __restrict__ res_lo, const float* __restrict__ res_hi,
        float* __restrict__ Cf, unsigned short* __restrict__ Cb,
        unsigned short* __restrict__ vt_g,
        int N, int K, int rsplit) {
    __shared__ unsigned short As[64 * 64];
    __shared__ unsigned short Ws[64 * 64];
    const int t = threadIdx.x;
    const int w = t >> 6, lane = t & 63, quad = lane >> 4, l16 = lane & 15;
    const int wm = w >> 1, wn = w & 1;
    const int m0 = blockIdx.y * 64, n0 = blockIdx.x * 64;
    const int srow = lane >> 3;                     // 0..7 within 8-row group
    const int schunk = (lane & 7) ^ srow;           // swizzled global chunk

    f32x4 acc[2][2];
    #pragma unroll
    for (int i = 0; i < 2; i++)
        #pragma unroll
        for (int j = 0; j < 2; j++)
            acc[i][j] = (f32x4){0.f, 0.f, 0.f, 0.f};

    for (int k0 = 0; k0 < K; k0 += 64) {
        #pragma unroll
        for (int q = 0; q < 2; q++) {
            const int r0 = w * 16 + q * 8;
            glds16(&A [(size_t)(m0 + r0 + srow) * K + k0 + schunk * 8], &As[r0 * 64]);
            glds16(&Wt[(size_t)(n0 + r0 + srow) * K + k0 + schunk * 8], &Ws[r0 * 64]);
        }
        __syncthreads();
        #pragma unroll
        for (int kc = 0; kc < 2; kc++) {
            bf16x8 af[2], bfr[2];
            #pragma unroll
            for (int i = 0; i < 2; i++) {
                const int ra = wm * 32 + i * 16 + l16;
                const int rb = wn * 32 + i * 16 + l16;
                af[i]  = *(const bf16x8*)&As[ra * 64 + (((kc * 4 + quad) ^ (l16 & 7)) * 8)];
                bfr[i] = *(const bf16x8*)&Ws[rb * 64 + (((kc * 4 + quad) ^ (l16 & 7)) * 8)];
            }
            #pragma unroll
            for (int i = 0; i < 2; i++)
                #pragma unroll
                for (int j = 0; j < 2; j++)
                    acc[i][j] = __builtin_amdgcn_mfma_f32_16x16x32_bf16(af[i], bfr[j], acc[i][j], 0, 0, 0);
        }
        __syncthreads();
    }

    const float* res = nullptr;
    if (MODE == 0 && res_lo)
        res = (m0 < rsplit) ? res_lo : (res_hi - (size_t)rsplit * N);

    #pragma unroll
    for (int i = 0; i < 2; i++) {
        #pragma unroll
        for (int j = 0; j < 2; j++) {
            const int n = n0 + wn * 32 + j * 16 + l16;
            const float bv = bias[n];
            #pragma unroll
            for (int r = 0; r < 4; r++) {
                const int m = m0 + wm * 32 + i * 16 + quad * 4 + r;
                float v = acc[i][j][r] + bv;
                if (GELU) v = 0.5f * v * (1.0f + erff(v * 0.70710678118654752f));
                if (MODE == 0) {
                    if (res) v += res[(size_t)m * N + n];
                    Cf[(size_t)m * N + n] = v;
                } else if (MODE == 1) {
                    Cb[(size_t)m * N + n] = f2bf(v);
                } else {                      // MODE 2: QKV split
                    if (n0 < 512) {
                        Cb[(size_t)m * 512 + n] = f2bf(v);
                    } else {
                        const int nn = n - 512, h = nn >> 5, d = nn & 31;
                        const int side = m >> 12, bb = (m >> 10) & 3, seq = m & 1023;
                        vt_g[(size_t)(side * 32 + bb * 8 + h) * 32768 + d * 1024 + seq] = f2bf(v);
                    }
                }
            }
        }
    }
}

// ---------------------------------------------------------------- attention
// MFMA flash attention, static-max softmax (logits bounded << 88 here).
// qk: bf16 [8192][512] (Q|K).  vt: bf16 [64 bh][32 hd][1024 seq].
// Grid (16, 64): x = 64-row q-tile, y = bh (side*32+b*8+h). 4 waves, 16 q-rows
// each.  K/V^T staged via global_load_lds (XOR chunk swizzle); bias staged
// wave-private, double-buffered, issued post-barrier so HBM latency hides
// behind the compute phase.
template <bool HAS_BIAS>
__global__ __launch_bounds__(256) void attn_mfma(
        const unsigned short* __restrict__ qk, const unsigned short* __restrict__ vt,
        const float* __restrict__ bias_src, const float* __restrict__ bias_tgt,
        unsigned short* __restrict__ AO, int cross) {
    extern __shared__ char smem[];
    unsigned short* Kss = (unsigned short*)smem;            // [64][32] swizzled
    unsigned short* Vts = (unsigned short*)(smem + 4096);   // [32][64] swizzled
    unsigned short* Pss = (unsigned short*)(smem + 8192);   // [64][72]
    float*          Bls = (float*)(smem + 17408);           // [2][4][16][64]

    const int t = threadIdx.x;
    const int w = t >> 6, lane = t & 63, quad = lane >> 4, l16 = lane & 15;
    const int bh = blockIdx.y;
    const int side = bh >> 5, b = (bh >> 3) & 3, h = bh & 7;
    const int q0 = blockIdx.x * 64;
    const int qbase  = side * ROWS + b * SEQ;
    const int kvside = cross ? (1 - side) : side;
    const int kvbase = kvside * ROWS + b * SEQ;
    const int bhv = kvside * 32 + b * 8 + h;

    // Q fragment straight from global (A-operand layout)
    const bf16x8 aq = *(const bf16x8*)&qk[(size_t)(qbase + q0 + w * 16 + l16) * 512 + h * HD + quad * 8];

    const float* brow = nullptr;
    if (HAS_BIAS)
        brow = (side ? bias_tgt : bias_src)
             + ((size_t)(b * NHEAD + h) * SEQ + q0 + w * 16) * SEQ;

    // staging lane geometry
    const int krow  = w * 16 + (lane >> 2);                 // key row staged
    const int kslot = (lane & 3) ^ ((lane >> 2) & 3);
    const int vrow  = w * 8 + (lane >> 3);                  // hd row staged
    const int vslot = (lane & 7) ^ ((lane >> 3) & 7);
    const int b_r   = lane >> 4;                            // bias sub-row
    const int b_c   = (lane & 15) * 4;                      // bias col (f32)

    float lsum[4] = {0.f, 0.f, 0.f, 0.f};
    f32x4 o0 = (f32x4){0.f, 0.f, 0.f, 0.f};
    f32x4 o1 = (f32x4){0.f, 0.f, 0.f, 0.f};

    if (HAS_BIAS) {
        #pragma unroll
        for (int q = 0; q < 4; q++)
            glds16(&brow[(size_t)(q * 4 + b_r) * SEQ + b_c],
                   &Bls[w * 1024 + q * 256]);
    }

    for (int kt = 0; kt < SEQ / 64; kt++) {
        __syncthreads();                        // Ks/Vts free for reuse
        glds16(&qk[(size_t)(kvbase + kt * 64 + krow) * 512 + 256 + h * HD + kslot * 8],
               &Kss[w * 16 * 32]);
        glds16(&vt[(size_t)bhv * 32768 + (size_t)vrow * 1024 + kt * 64 + vslot * 8],
               &Vts[w * 8 * 64]);
        __syncthreads();                        // staged tiles ready
        if (HAS_BIAS && kt + 1 < SEQ / 64) {    // prefetch next bias tile:
            #pragma unroll                      // drains only at next barrier,
            for (int q = 0; q < 4; q++)         // hidden behind compute
                glds16(&brow[(size_t)(q * 4 + b_r) * SEQ + (kt + 1) * 64 + b_c],
                       &Bls[((kt + 1) & 1) * 4096 + w * 1024 + q * 256]);
        }

        // S = Q @ K^T
        f32x4 s[4];
        #pragma unroll
        for (int st = 0; st < 4; st++) {
            const bf16x8 kf = *(const bf16x8*)&Kss[(st * 16 + l16) * 32 + ((quad ^ (l16 & 3)) * 8)];
            f32x4 z = (f32x4){0.f, 0.f, 0.f, 0.f};
            s[st] = __builtin_amdgcn_mfma_f32_16x16x32_bf16(aq, kf, z, 0, 0, 0);
        }

        const float* bb = HAS_BIAS ? &Bls[(kt & 1) * 4096 + w * 1024] : nullptr;
        #pragma unroll
        for (int st = 0; st < 4; st++) {
            #pragma unroll
            for (int r = 0; r < 4; r++) {
                float v = s[st][r] * ATT_SCALE;
                if (HAS_BIAS) v += bb[(quad * 4 + r) * 64 + st * 16 + l16];
                const float p = __expf(v);      // static-max: logits << 88
                lsum[r] += p;
                Pss[(w * 16 + quad * 4 + r) * 72 + st * 16 + l16] = f2bf(p);
            }
        }

        // O += P @ V  (A = Ps rows, B = V^T rows, both b128)
        #pragma unroll
        for (int c = 0; c < 2; c++) {
            const bf16x8 ap  = *(const bf16x8*)&Pss[(w * 16 + l16) * 72 + c * 32 + quad * 8];
            const int slot = (((c * 4 + quad) ^ (l16 & 7)) * 8);
            const bf16x8 bv0 = *(const bf16x8*)&Vts[l16 * 64 + slot];
            const bf16x8 bv1 = *(const bf16x8*)&Vts[(16 + l16) * 64 + slot];
            o0 = __builtin_amdgcn_mfma_f32_16x16x32_bf16(ap, bv0, o0, 0, 0, 0);
            o1 = __builtin_amdgcn_mfma_f32_16x16x32_bf16(ap, bv1, o1, 0, 0, 0);
        }
    }

    #pragma unroll
    for (int r = 0; r < 4; r++) {
        float l = lsum[r];
        #pragma unroll
        for (int off = 1; off < 16; off <<= 1) l += __shfl_xor(l, off, 64);
        const float inv = 1.0f / l;
        const size_t orow = (size_t)(qbase + q0 + w * 16 + quad * 4 + r) * DIM + h * HD;
        AO[orow + l16]      = f2bf(o0[r] * inv);
        AO[orow + 16 + l16] = f2bf(o1[r] * inv);
    }
}

// ---------------------------------------------------------------- launcher
extern "C" void kernel_launch(void* const* d_in, const int* in_sizes, int n_in,
                              void* d_out, int out_size, void* d_ws, size_t ws_size,
                              hipStream_t stream) {
    const float* src_feats    = (const float*)d_in[0];
    const float* tgt_feats    = (const float*)d_in[1];
    const float* src_geo_bias = (const float*)d_in[2];
    const float* tgt_geo_bias = (const float*)d_in[3];
    const float* sa_q_w = (const float*)d_in[4];
    const float* sa_q_b = (const float*)d_in[5];
    const float* sa_k_w = (const float*)d_in[6];
    const float* sa_k_b = (const float*)d_in[7];
    const float* sa_v_w = (const float*)d_in[8];
    const float* sa_v_b = (const float*)d_in[9];
    const float* sa_o_w = (const float*)d_in[10];
    const float* sa_o_b = (const float*)d_in[11];
    const float* ca_q_w = (const float*)d_in[12];
    const float* ca_q_b = (const float*)d_in[13];
    const float* ca_k_w = (const float*)d_in[14];
    const float* ca_k_b = (const float*)d_in[15];
    const float* ca_v_w = (const float*)d_in[16];
    const float* ca_v_b = (const float*)d_in[17];
    const float* ca_o_w = (const float*)d_in[18];
    const float* ca_o_b = (const float*)d_in[19];
    const float* ln_sa_g = (const float*)d_in[20];
    const float* ln_sa_b = (const float*)d_in[21];
    const float* ln_ca_g = (const float*)d_in[22];
    const float* ln_ca_b = (const float*)d_in[23];
    const float* ln_ff_g = (const float*)d_in[24];
    const float* ln_ff_b = (const float*)d_in[25];
    const float* ffn_w1  = (const float*)d_in[26];
    const float* ffn_b1  = (const float*)d_in[27];
    const float* ffn_w2  = (const float*)d_in[28];
    const float* ffn_b2  = (const float*)d_in[29];

    float* out = (float*)d_out;                      // [8192][256] fp32

    // ---- workspace carve ----
    char* ws = (char*)d_ws;
    unsigned short* Xn = (unsigned short*)(ws);                  // [0,4M)  [8192][256]
    unsigned short* QK = (unsigned short*)(ws + (4  << 20));     // [4,12M) [8192][512]
    unsigned short* VT = (unsigned short*)(ws + (12 << 20));     // [12,16M)[64][32][1024]
    unsigned short* AO = (unsigned short*)(ws + (16 << 20));     // [16,20M)[8192][256]
    unsigned short* Hh = (unsigned short*)(ws + (4  << 20));     // [4,20M) alias (FFN hidden)
    char* wp = ws + (20 << 20);
    unsigned short* sa_qkv_wt = (unsigned short*)wp;  wp += 768 * 256 * 2;
    unsigned short* ca_qkv_wt = (unsigned short*)wp;  wp += 768 * 256 * 2;
    unsigned short* sa_o_wt   = (unsigned short*)wp;  wp += 256 * 256 * 2;
    unsigned short* ca_o_wt   = (unsigned short*)wp;  wp += 256 * 256 * 2;
    unsigned short* ffn1_wt   = (unsigned short*)wp;  wp += 1024 * 256 * 2;
    unsigned short* ffn2_wt   = (unsigned short*)wp;  wp += 256 * 1024 * 2;
    float* sa_qkv_bias = (float*)wp;  wp += 768 * 4;
    float* ca_qkv_bias = (float*)wp;  wp += 768 * 4;

    const dim3 blk(256);
    const dim3 attn_grid(SEQ / 64, 64);
    const int smem_sa = 17408 + 2 * 4096 * 4;    // 50176 B (with bias dbuf)
    const int smem_ca = 17408;

    convert_weights<<<dim3(4103), blk, 0, stream>>>(
        sa_q_w, sa_k_w, sa_v_w, ca_q_w, ca_k_w, ca_v_w, sa_o_w, ca_o_w,
        ffn_w1, ffn_w2, sa_q_b, sa_k_b, sa_v_b, ca_q_b, ca_k_b, ca_v_b,
        sa_qkv_wt, ca_qkv_wt, sa_o_wt, ca_o_wt, ffn1_wt, ffn2_wt,
        sa_qkv_bias, ca_qkv_bias);

    // ---- 1. geometric self-attention (src+tgt batched) ----
    ln2_kernel<<<dim3(ROWS2 / 4), blk, 0, stream>>>(src_feats, tgt_feats, ln_sa_g, ln_sa_b, Xn);
    gemm_bf16<false, 2><<<dim3(QKVN / 64, ROWS2 / 64), blk, 0, stream>>>(
        Xn, sa_qkv_wt, sa_qkv_bias, nullptr, nullptr, nullptr, QK, VT, QKVN, DIM, ROWS);
    attn_mfma<true><<<attn_grid, blk, smem_sa, stream>>>(QK, VT, src_geo_bias, tgt_geo_bias, AO, 0);
    gemm_bf16<false, 0><<<dim3(DIM / 64, ROWS2 / 64), blk, 0, stream>>>(
        AO, sa_o_wt, sa_o_b, src_feats, tgt_feats, out, nullptr, nullptr, DIM, DIM, ROWS);

    // ---- 2. cross-attention ----
    ln_kernel<<<dim3(ROWS2 / 4), blk, 0, stream>>>(out, ln_ca_g, ln_ca_b, Xn);
    gemm_bf16<false, 2><<<dim3(QKVN / 64, ROWS2 / 64), blk, 0, stream>>>(
        Xn, ca_qkv_wt, ca_qkv_bias, nullptr, nullptr, nullptr, QK, VT, QKVN, DIM, ROWS);
    attn_mfma<false><<<attn_grid, blk, smem_ca, stream>>>(QK, VT, nullptr, nullptr, AO, 1);
    gemm_bf16<false, 0><<<dim3(DIM / 64, ROWS2 / 64), blk, 0, stream>>>(
        AO, ca_o_wt, ca_o_b, out, out + (size_t)ROWS * DIM, out, nullptr, nullptr, DIM, DIM, ROWS);

    // ---- 3. FFN ----
    ln_kernel<<<dim3(ROWS2 / 4), blk, 0, stream>>>(out, ln_ff_g, ln_ff_b, Xn);
    gemm_bf16<true, 1><<<dim3(FFND / 64, ROWS2 / 64), blk, 0, stream>>>(
        Xn, ffn1_wt, ffn_b1, nullptr, nullptr, nullptr, Hh, nullptr, FFND, DIM, ROWS);
    gemm_bf16<false, 0><<<dim3(DIM / 64, ROWS2 / 64), blk, 0, stream>>>(
        Hh, ffn2_wt, ffn_b2, out, out + (size_t)ROWS * DIM, out, nullptr, nullptr, DIM, FFND, ROWS);
}